// Round 2
// baseline (697.788 us; speedup 1.0000x reference)
//
#include <hip/hip_runtime.h>

typedef __attribute__((ext_vector_type(4))) float f4;
typedef __attribute__((ext_vector_type(4))) float f32x4;
typedef __attribute__((ext_vector_type(8))) short short8;
typedef __attribute__((ext_vector_type(4))) short short4v;

#define S_  4096
#define NB_ 16
#define SLOPE_SCALE 0.838719677419355f
#define ST1 136   // LDS row stride (shorts) for transposed bf16 tiles (128 n + 8 pad)

__device__ __forceinline__ float slope_for_head(int h) {
    return exp2f(-(float)(h + 1) * 0.125f) * SLOPE_SCALE;
}

// fp32 -> bf16 round-to-nearest-even
__device__ __forceinline__ short f2bf(float f) {
    unsigned u = __float_as_uint(f);
    u += 0x7FFFu + ((u >> 16) & 1u);
    return (short)(u >> 16);
}

// ---------------------------------------------------------------------------
// Phase 1 (MFMA): per (bh, j):
//   KVT[e][d] = sum_n  V^T[e][n] * (k_decay[n] * K[n][d])     (bf16 MFMA, fp32 acc)
// Stages transposed bf16 tiles (V^T, (kd*K)^T) in LDS via packed-pair dword
// writes; 2 halves of 128 n each to keep LDS at 2*34KB/2 = 34.8 KB.
// Side products: vt (bf16 V^T, global, for phase3 A-frags) and kb (bf16 K,
// n-major, for phase3's S^T A-frags).
// ---------------------------------------------------------------------------
__global__ __launch_bounds__(256, 4) void phase1_kvblocks(
    const float* __restrict__ k, const float* __restrict__ v,
    const int* __restrict__ mask, float* __restrict__ kvt,
    short* __restrict__ vt, short* __restrict__ kb)
{
    __shared__ short kts[64 * ST1];  // (kd*K)^T  [d][n_local]
    __shared__ short vts[64 * ST1];  // V^T       [e][n_local]
    const int j    = blockIdx.x;   // 0..15
    const int bh   = blockIdx.y;   // 0..127
    const int b    = bh >> 6;
    const int h    = bh & 63;
    const int t    = threadIdx.x;
    const int wave = t >> 6;
    const int lane = t & 63;
    const int quad = lane >> 4;
    const int l16  = lane & 15;
    const float slope = slope_for_head(h);

    const long long tilebase = ((long long)bh * S_ + j * 256) * 64;

    const f32x4 zf = {0.f, 0.f, 0.f, 0.f};
    f32x4 acc[4];
    acc[0] = zf; acc[1] = zf; acc[2] = zf; acc[3] = zf;

    for (int half = 0; half < 2; ++half) {
        const int noff = half * 128;

        // ---- stage 128 rows: each unit handles 2 consecutive rows x 4 cols ----
        for (int i = 0; i < 4; ++i) {
            int u  = t + i * 256;        // 0..1023
            int np = u >> 4;             // 0..63 (local row pair)
            int dg = (u & 15) << 2;      // 0..60
            int nl = np << 1;            // local n (even)
            int na = noff + nl;          // n within 256-block
            long long g0 = tilebase + (long long)na * 64 + dg;

            f4 k0 = *(const f4*)(k + g0);
            f4 k1 = *(const f4*)(k + g0 + 64);
            f4 v0 = *(const f4*)(v + g0);
            f4 v1 = *(const f4*)(v + g0 + 64);
            float m0 = (float)mask[b * S_ + j * 256 + na];
            float m1 = (float)mask[b * S_ + j * 256 + na + 1];
            v0 *= m0; v1 *= m1;
            float kd0 = __expf(-slope * (float)(255 - na));
            float kd1 = __expf(-slope * (float)(254 - na));

            // kb: undecayed bf16 K, n-major (for phase3)
            short4v kb0 = {f2bf(k0.x), f2bf(k0.y), f2bf(k0.z), f2bf(k0.w)};
            short4v kb1 = {f2bf(k1.x), f2bf(k1.y), f2bf(k1.z), f2bf(k1.w)};
            *(short4v*)(kb + g0) = kb0;
            *(short4v*)(kb + g0 + 64) = kb1;

            f4 kda = k0 * kd0;
            f4 kdb = k1 * kd1;
            for (int x = 0; x < 4; ++x) {
                unsigned kw = (unsigned)(unsigned short)f2bf(kda[x]) |
                              ((unsigned)(unsigned short)f2bf(kdb[x]) << 16);
                unsigned vw = (unsigned)(unsigned short)f2bf(v0[x]) |
                              ((unsigned)(unsigned short)f2bf(v1[x]) << 16);
                *(unsigned*)&kts[(dg + x) * ST1 + nl] = kw;
                *(unsigned*)&vts[(dg + x) * ST1 + nl] = vw;
            }
        }
        __syncthreads();

        // ---- MFMA: D[e][d] over this half's 128 n (4 k-steps of 32) ----
        for (int ks = 0; ks < 4; ++ks) {
            int n0 = ks * 32;
            short8 af = *(const short8*)&vts[(wave * 16 + l16) * ST1 + n0 + quad * 8];
            for (int dt = 0; dt < 4; ++dt) {
                short8 bf = *(const short8*)&kts[(dt * 16 + l16) * ST1 + n0 + quad * 8];
                acc[dt] = __builtin_amdgcn_mfma_f32_16x16x32_bf16(af, bf, acc[dt], 0, 0, 0);
            }
        }

        // ---- vt global: vectorized rows of V^T ----
        {
            int e  = t >> 2;
            int ng = (t & 3) << 5;    // 0,32,64,96
            long long gv = (long long)(bh * 64 + e) * S_ + j * 256 + noff + ng;
            for (int x = 0; x < 4; ++x)
                *(short8*)(vt + gv + x * 8) = *(const short8*)&vts[e * ST1 + ng + x * 8];
        }
        __syncthreads();
    }

    // ---- store KV block contribution: kvt[e][d] row-major, fp32 ----
    float* o = kvt + ((long long)(bh * NB_ + j)) * 4096;
    for (int dt = 0; dt < 4; ++dt)
        for (int r = 0; r < 4; ++r)
            o[(wave * 16 + quad * 4 + r) * 64 + dt * 16 + l16] = acc[dt][r];
}

// ---------------------------------------------------------------------------
// Phase 2: prefix scan over block index j (element-wise; 512 blocks).
//   state entering block j: S_j = bd*S_{j-1} + KVb_{j-1}, S_0 = 0
// ---------------------------------------------------------------------------
__global__ __launch_bounds__(256) void phase2_scan(float* __restrict__ kvt)
{
    const int g    = blockIdx.x;     // 0..511
    const int bh   = g >> 2;
    const int part = g & 3;
    const int h    = bh & 63;
    const float bd = __expf(-slope_for_head(h) * 256.0f);

    f32x4 st = {0.f, 0.f, 0.f, 0.f};
    f4* base = (f4*)(kvt + (long long)bh * NB_ * 4096) + part * 256 + threadIdx.x;
    for (int j = 0; j < NB_; ++j) {
        f4* p = base + j * 1024;
        f4 tmp = *p;
        *p = st;
        st = st * bd + tmp;
    }
}

// ---------------------------------------------------------------------------
// Phase 3: per (bh, j), 4 independent waves each owning 64 m-rows.
//   inter: O^T[e][m] += kvT[e][d] * q[m][d]   (cols scaled by q_decay[m])
//   S^T = K @ Q^T -> decay -> P[m][n] bf16 (per-wave LDS, no barriers)
//   O^T += V^T @ P^T
// ---------------------------------------------------------------------------
__global__ __launch_bounds__(256, 4) void phase3_output(
    const float* __restrict__ q, const short* __restrict__ kb,
    const float* __restrict__ kvt, const short* __restrict__ vt,
    float* __restrict__ out)
{
    __shared__ short P[4][64 * 56];   // per-wave [64 m][56 stride, 32 n used]
    const int j    = blockIdx.x;      // 0..15
    const int bh   = blockIdx.y;      // 0..127
    const int h    = bh & 63;
    const int tid  = threadIdx.x;
    const int wave = tid >> 6;
    const int lane = tid & 63;
    const int quad = lane >> 4;
    const int l16  = lane & 15;
    const int wrole  = (wave + j) & 3;   // balance causal trip counts across SIMDs
    const float slope = slope_for_head(h);
    const int mwbase = wrole << 6;       // wave's m base within the 256-block

    const long long rowbase = (long long)bh * S_ + j * 256 + mwbase;

    // ---- Q fragments (B-operand layout: B[k=ks*32+quad*8+jj][m=l16]) ----
    short8 qf[4][2];
    for (int mt = 0; mt < 4; ++mt) {
        const float* qp = q + (rowbase + mt * 16 + l16) * 64 + quad * 8;
        for (int ks = 0; ks < 2; ++ks) {
            f4 a = *(const f4*)(qp + ks * 32);
            f4 b = *(const f4*)(qp + ks * 32 + 4);
            short8 f;
            f[0] = f2bf(a.x); f[1] = f2bf(a.y); f[2] = f2bf(a.z); f[3] = f2bf(a.w);
            f[4] = f2bf(b.x); f[5] = f2bf(b.y); f[6] = f2bf(b.z); f[7] = f2bf(b.w);
            qf[mt][ks] = f;
        }
    }

    // ---- O^T accumulators: of[et][mt], C frag (row = e local, col = m local)
    const f32x4 zf = {0.f, 0.f, 0.f, 0.f};
    f32x4 of[4][4];
    for (int et = 0; et < 4; ++et)
        for (int mt = 0; mt < 4; ++mt) of[et][mt] = zf;

    // ---- inter-block: O^T += kvT @ Q^T ----
    const float* kvp = kvt + ((long long)(bh * NB_ + j) << 12);
    for (int et = 0; et < 4; ++et) {
        for (int ks = 0; ks < 2; ++ks) {
            const float* p = kvp + (et * 16 + l16) * 64 + ks * 32 + quad * 8;
            f4 a = *(const f4*)(p);
            f4 b = *(const f4*)(p + 4);
            short8 af;
            af[0] = f2bf(a.x); af[1] = f2bf(a.y); af[2] = f2bf(a.z); af[3] = f2bf(a.w);
            af[4] = f2bf(b.x); af[5] = f2bf(b.y); af[6] = f2bf(b.z); af[7] = f2bf(b.w);
            for (int mt = 0; mt < 4; ++mt)
                of[et][mt] = __builtin_amdgcn_mfma_f32_16x16x32_bf16(
                    af, qf[mt][ks], of[et][mt], 0, 0, 0);
        }
    }
    // scale columns (m) by q_decay[m] = exp(-slope*(m+1))
    for (int mt = 0; mt < 4; ++mt) {
        float qd = __expf(-slope * (float)(mwbase + mt * 16 + l16 + 1));
        for (int et = 0; et < 4; ++et) of[et][mt] *= qd;
    }

    // ---- intra-block, causal, chunks of 32 n ----
    const float er1 = __expf(slope);
    const float er2 = er1 * er1;
    const float er3 = er2 * er1;
    short* Pw = &P[wave][0];                 // index by PHYSICAL wave (privacy)
    const int nchunks = (mwbase >> 5) + 2;   // covers n < mwbase + 64

    for (int c = 0; c < nchunks; ++c) {
        const int nbase = c << 5;

        // K A-fragments from bf16 kb (A[n=l16][k=ks*32+quad*8+jj])
        short8 kf[2][2];
        for (int nt = 0; nt < 2; ++nt) {
            const short* kp = kb + ((long long)bh * S_ + j * 256 + nbase + nt * 16 + l16) * 64 + quad * 8;
            kf[nt][0] = *(const short8*)(kp);
            kf[nt][1] = *(const short8*)(kp + 32);
        }

        // S^T = K @ Q^T  (C frag: row = n local = quad*4+reg, col = m = l16)
        f32x4 sf[2][4];
        for (int nt = 0; nt < 2; ++nt)
            for (int mt = 0; mt < 4; ++mt) sf[nt][mt] = zf;
        for (int nt = 0; nt < 2; ++nt)
            for (int ks = 0; ks < 2; ++ks)
                for (int mt = 0; mt < 4; ++mt)
                    sf[nt][mt] = __builtin_amdgcn_mfma_f32_16x16x32_bf16(
                        kf[nt][ks], qf[mt][ks], sf[nt][mt], 0, 0, 0);

        // apply causal decay, cast bf16, store to per-wave P buffer [m][n]
        for (int nt = 0; nt < 2; ++nt) {
            for (int mt = 0; mt < 4; ++mt) {
                int n0 = nbase + nt * 16 + quad * 4;       // n at reg 0
                int m  = mwbase + mt * 16 + l16;
                float ddb = __expf(-slope * (float)(m - n0));
                f32x4 s = sf[nt][mt];
                float v0 = (m >= n0)     ? s[0] * ddb       : 0.f;
                float v1 = (m >= n0 + 1) ? s[1] * ddb * er1 : 0.f;
                float v2 = (m >= n0 + 2) ? s[2] * ddb * er2 : 0.f;
                float v3 = (m >= n0 + 3) ? s[3] * ddb * er3 : 0.f;
                short4v pk = {f2bf(v0), f2bf(v1), f2bf(v2), f2bf(v3)};
                *(short4v*)&Pw[(mt * 16 + l16) * 56 + nt * 16 + quad * 4] = pk;
            }
        }
        asm volatile("s_waitcnt lgkmcnt(0)" ::: "memory");

        // P B-fragments (B[k=n=quad*8+jj][m=l16]) — contiguous b128 reads
        short8 pb[4];
        for (int mt = 0; mt < 4; ++mt)
            pb[mt] = *(const short8*)&Pw[(mt * 16 + l16) * 56 + quad * 8];
        // V^T A-fragments straight from global bf16 (A[e=l16][n=quad*8+jj])
        short8 va[4];
        for (int et = 0; et < 4; ++et)
            va[et] = *(const short8*)(vt + ((long long)(bh * 64 + et * 16 + l16)) * S_
                                         + j * 256 + nbase + quad * 8);

        for (int et = 0; et < 4; ++et)
            for (int mt = 0; mt < 4; ++mt)
                of[et][mt] = __builtin_amdgcn_mfma_f32_16x16x32_bf16(
                    va[et], pb[mt], of[et][mt], 0, 0, 0);
    }

    // ---- epilogue: O^T frag (row=e, col=m) -> out[m][e], float4 stores ----
    for (int mt = 0; mt < 4; ++mt) {
        float* orow = out + (rowbase + mt * 16 + l16) * 64;
        for (int et = 0; et < 4; ++et) {
            f4 o = {of[et][mt][0], of[et][mt][1], of[et][mt][2], of[et][mt][3]};
            *(f4*)(orow + et * 16 + quad * 4) = o;
        }
    }
}

// ---------------------------------------------------------------------------
extern "C" void kernel_launch(void* const* d_in, const int* in_sizes, int n_in,
                              void* d_out, int out_size, void* d_ws, size_t ws_size,
                              hipStream_t stream) {
    const float* q    = (const float*)d_in[0];
    const float* k    = (const float*)d_in[1];
    const float* v    = (const float*)d_in[2];
    const int*   mask = (const int*)d_in[3];
    float* kvt = (float*)d_ws;                                        // 32 MB fp32
    short* vt  = (short*)((char*)d_ws + (size_t)128 * 16 * 4096 * 4); // 64 MB bf16 V^T
    short* kb  = (short*)((char*)vt + (size_t)128 * 4096 * 64 * 2);   // 64 MB bf16 K
    float* out = (float*)d_out;

    phase1_kvblocks<<<dim3(16, 128), 256, 0, stream>>>(k, v, mask, kvt, vt, kb);
    phase2_scan<<<512, 256, 0, stream>>>(kvt);
    phase3_output<<<dim3(16, 128), 256, 0, stream>>>(q, kb, kvt, vt, out);
}